// Round 3
// baseline (664.808 us; speedup 1.0000x reference)
//
#include <hip/hip_runtime.h>

// QuantisedLinear: out[n,o] = sum_i x[n,i] * w[o,i]
//   wq[o][q] byte b: w[o,2q] = (b>>4)*2/15-1, w[o,2q+1] = (b&15)*2/15-1,
//   scaled by scale[o, col/128]. Scale folded: w = fma(nib, s*2/15, -s).
// M=8, N=28672, K=8192. HBM-bound: 470 MB weight stream read once.
// v3: scales via wave-uniform s_load (+cndmask select) so they never enter the
// vmcnt chain; x AND weights double-buffered in registers, issue order x->w so
// consumer waits never drain the weight prefetch; #pragma unroll 2 ping-pongs
// buffers without v_mov copies.

#define O_TOTAL 28672
#define I_TOTAL 8192
#define QROW    4096      // int32 per weight row
#define NBLK    64        // scale blocks per row (K/128)
#define NITER   32        // 128 int32 (256 cols) per row per iter

__global__ __launch_bounds__(256)
void qlinear_kernel(const float* __restrict__ x,
                    const int*   __restrict__ wq,
                    const float* __restrict__ scale,
                    float*       __restrict__ out) {
    const int tid  = threadIdx.x;
    const int wave = __builtin_amdgcn_readfirstlane(tid >> 6);  // force SGPR
    const int lane = tid & 63;
    const int o0   = blockIdx.x * 16 + wave * 4;   // 4 rows/wave, 16/block

    const int*   wbase = wq + (size_t)o0 * QROW + 2 * lane;  // int2 per row
    const float* xbase = x + 4 * lane;                       // float4 per batch
    const float* sbase = scale + o0 * NBLK;                  // uniform -> s_load

    float acc[32];                                 // [r][n] flat r*8+n
    #pragma unroll
    for (int i = 0; i < 32; ++i) acc[i] = 0.0f;

    float4 xcur[8], xnxt[8];
    int2   wcur[4], wnxt[4];
    float  scA[4], scB[4], snA[4], snB[4];         // uniform -> SGPRs

    // prime j=0
    #pragma unroll
    for (int n = 0; n < 8; ++n)
        xcur[n] = *(const float4*)(xbase + n * I_TOTAL);
    #pragma unroll
    for (int r = 0; r < 4; ++r)
        wcur[r] = *(const int2*)(wbase + r * QROW);
    #pragma unroll
    for (int r = 0; r < 4; ++r) {
        scA[r] = sbase[r * NBLK + 0];
        scB[r] = sbase[r * NBLK + 1];
    }

    #pragma unroll 2
    for (int j = 0; j < NITER; ++j) {
        // last iter re-prefetches j=31: those lines are L2-hot (just fetched),
        // unlike a wrap to j=0 which would be long-evicted -> extra HBM.
        const int jn = (j < NITER - 1) ? j + 1 : NITER - 1;

        // Prefetch next iteration. x FIRST, weights LAST: vmcnt is in-order,
        // so waiting on x (L2/L3) never forces a wait on the HBM weight stream.
        #pragma unroll
        for (int n = 0; n < 8; ++n)
            xnxt[n] = *(const float4*)(xbase + n * I_TOTAL + 256 * jn);
        #pragma unroll
        for (int r = 0; r < 4; ++r)
            wnxt[r] = *(const int2*)(wbase + r * QROW + 128 * jn);
        // scales: wave-uniform addresses -> scalar loads (lgkm, not vmcnt)
        #pragma unroll
        for (int r = 0; r < 4; ++r) {
            snA[r] = sbase[r * NBLK + 2 * jn];
            snB[r] = sbase[r * NBLK + 2 * jn + 1];
        }

        // compute on current buffers: cols 256j + 4L .. +3
        #pragma unroll
        for (int r = 0; r < 4; ++r) {
            const float s   = (lane < 32) ? scA[r] : scB[r];  // block 2j vs 2j+1
            const float s2  = s * (2.0f / 15.0f);
            const int   w01 = wcur[r].x;
            const int   w23 = wcur[r].y;
            const float wA  = fmaf((float)((w01 >> 4) & 15), s2, -s);
            const float wB  = fmaf((float)( w01       & 15), s2, -s);
            const float wC  = fmaf((float)((w23 >> 4) & 15), s2, -s);
            const float wD  = fmaf((float)( w23       & 15), s2, -s);
            #pragma unroll
            for (int n = 0; n < 8; ++n) {
                float t = fmaf(wA, xcur[n].x, acc[r * 8 + n]);
                t       = fmaf(wB, xcur[n].y, t);
                t       = fmaf(wC, xcur[n].z, t);
                acc[r * 8 + n] = fmaf(wD, xcur[n].w, t);
            }
        }

        // rotate (elided by unroll-2 ping-pong)
        #pragma unroll
        for (int n = 0; n < 8; ++n) xcur[n] = xnxt[n];
        #pragma unroll
        for (int r = 0; r < 4; ++r) wcur[r] = wnxt[r];
        #pragma unroll
        for (int r = 0; r < 4; ++r) { scA[r] = snA[r]; scB[r] = snB[r]; }
    }

    // In-place butterfly: 32 values x 64 lanes -> lane L holds value L&31,
    // then one xor-32 add completes the 64-lane sum.
    #pragma unroll
    for (int bs = 0; bs < 5; ++bs) {
        const int keep = (lane >> bs) & 1;
        const int m = 32 >> (bs + 1);
        #pragma unroll
        for (int i = 0; i < m; ++i) {
            float lo   = acc[2 * i];
            float hi   = acc[2 * i + 1];
            float mine = keep ? hi : lo;
            float send = keep ? lo : hi;
            acc[i] = mine + __shfl_xor(send, 1 << bs, 64);
        }
    }
    float v = acc[0] + __shfl_xor(acc[0], 32, 64);

    if (lane < 32) {
        const int r = lane >> 3;   // value index = r*8+n = lane&31
        const int n = lane & 7;
        out[n * O_TOTAL + o0 + r] = v;
    }
}

extern "C" void kernel_launch(void* const* d_in, const int* in_sizes, int n_in,
                              void* d_out, int out_size, void* d_ws, size_t ws_size,
                              hipStream_t stream) {
    const float* x     = (const float*)d_in[0];
    const int*   wq    = (const int*)  d_in[1];
    const float* scale = (const float*)d_in[2];
    // d_in[3] (lut) reproduced arithmetically: lut[b] = ((b>>4)*2/15-1, (b&15)*2/15-1)
    float* out = (float*)d_out;

    dim3 grid(O_TOTAL / 16);   // 1792 blocks x 16 rows
    dim3 block(256);
    qlinear_kernel<<<grid, block, 0, stream>>>(x, wq, scale, out);
}

// Round 4
// 645.731 us; speedup vs baseline: 1.0295x; 1.0295x over previous
//
#include <hip/hip_runtime.h>

// QuantisedLinear: out[n,o] = sum_i x[n,i] * w[o,i]
//   wq[o][q] byte b: w[o,2q] = (b>>4)*2/15-1, w[o,2q+1] = (b&15)*2/15-1,
//   scaled by scale[o, col/128]. Scale folded: w = fma(nib, s*2/15, -s).
// M=8, N=28672, K=8192. HBM-bound: 470 MB weight stream read once (~75 us floor).
// v4 = best-measured R2 structure (w double-buffered int2, x loaded in-iter)
//   + scalar s_load scales (out of the vmcnt chain)
//   + x issued BEFORE w-prefetch (in-order vmcnt: x wait must not drain w stream)
//   + clamped prefetch on last iter (re-fetch L2-hot line, not evicted j=0)
// ~100-110 VGPR -> 4 waves/SIMD.

#define O_TOTAL 28672
#define I_TOTAL 8192
#define QROW    4096      // int32 per weight row
#define NBLK    64        // scale blocks per row (K/128)
#define NITER   32        // 128 int32 (256 cols) per row per iter

__global__ __launch_bounds__(256)
void qlinear_kernel(const float* __restrict__ x,
                    const int*   __restrict__ wq,
                    const float* __restrict__ scale,
                    float*       __restrict__ out) {
    const int tid  = threadIdx.x;
    const int wave = __builtin_amdgcn_readfirstlane(tid >> 6);
    const int lane = tid & 63;
    const int o0   = blockIdx.x * 16 + wave * 4;   // 4 rows/wave, 16/block

    const int*   wbase = wq + (size_t)o0 * QROW + 2 * lane;  // int2 per row
    const float* xbase = x + 4 * lane;                       // float4 per batch
    const float* sbase = scale + o0 * NBLK;                  // uniform -> s_load

    float acc[32];                                 // [r][n] flat r*8+n
    #pragma unroll
    for (int i = 0; i < 32; ++i) acc[i] = 0.0f;

    // prime weight buffer for j=0
    int2 wcur[4];
    #pragma unroll
    for (int r = 0; r < 4; ++r)
        wcur[r] = *(const int2*)(wbase + r * QROW);

    #pragma unroll 2
    for (int j = 0; j < NITER; ++j) {
        // x for this iteration: cols 256j + 4*lane .. +3 (L2/L3-resident)
        float4 xv[8];
        #pragma unroll
        for (int n = 0; n < 8; ++n)
            xv[n] = *(const float4*)(xbase + n * I_TOTAL + 256 * j);

        // prefetch next iteration's weights AFTER x: waiting on x (vmcnt
        // in-order) then leaves these in flight. Last iter re-fetches j=31
        // (L2-hot) instead of long-evicted j=0.
        const int jn = (j < NITER - 1) ? j + 1 : NITER - 1;
        int2 wnxt[4];
        #pragma unroll
        for (int r = 0; r < 4; ++r)
            wnxt[r] = *(const int2*)(wbase + r * QROW + 128 * jn);

        // scales: wave-uniform addresses -> s_load (lgkm, not vmcnt);
        // block = col/128 = 2j + (lane>>5) -> per-lane select of two SGPRs
        #pragma unroll
        for (int r = 0; r < 4; ++r) {
            const float sA = sbase[r * NBLK + 2 * j];
            const float sB = sbase[r * NBLK + 2 * j + 1];
            const float s  = (lane < 32) ? sA : sB;
            const float s2 = s * (2.0f / 15.0f);
            const int   w01 = wcur[r].x;
            const int   w23 = wcur[r].y;
            const float wA  = fmaf((float)((w01 >> 4) & 15), s2, -s);
            const float wB  = fmaf((float)( w01       & 15), s2, -s);
            const float wC  = fmaf((float)((w23 >> 4) & 15), s2, -s);
            const float wD  = fmaf((float)( w23       & 15), s2, -s);
            #pragma unroll
            for (int n = 0; n < 8; ++n) {
                float t = fmaf(wA, xv[n].x, acc[r * 8 + n]);
                t       = fmaf(wB, xv[n].y, t);
                t       = fmaf(wC, xv[n].z, t);
                acc[r * 8 + n] = fmaf(wD, xv[n].w, t);
            }
        }

        #pragma unroll
        for (int r = 0; r < 4; ++r) wcur[r] = wnxt[r];
    }

    // In-place butterfly: 32 values x 64 lanes -> lane L holds value L&31,
    // then one xor-32 add completes the 64-lane sum.
    #pragma unroll
    for (int bs = 0; bs < 5; ++bs) {
        const int keep = (lane >> bs) & 1;
        const int m = 32 >> (bs + 1);
        #pragma unroll
        for (int i = 0; i < m; ++i) {
            float lo   = acc[2 * i];
            float hi   = acc[2 * i + 1];
            float mine = keep ? hi : lo;
            float send = keep ? lo : hi;
            acc[i] = mine + __shfl_xor(send, 1 << bs, 64);
        }
    }
    float v = acc[0] + __shfl_xor(acc[0], 32, 64);

    if (lane < 32) {
        const int r = lane >> 3;   // value index = r*8+n = lane&31
        const int n = lane & 7;
        out[n * O_TOTAL + o0 + r] = v;
    }
}

extern "C" void kernel_launch(void* const* d_in, const int* in_sizes, int n_in,
                              void* d_out, int out_size, void* d_ws, size_t ws_size,
                              hipStream_t stream) {
    const float* x     = (const float*)d_in[0];
    const int*   wq    = (const int*)  d_in[1];
    const float* scale = (const float*)d_in[2];
    // d_in[3] (lut) reproduced arithmetically: lut[b] = ((b>>4)*2/15-1, (b&15)*2/15-1)
    float* out = (float*)d_out;

    dim3 grid(O_TOTAL / 16);   // 1792 blocks x 16 rows
    dim3 block(256);
    qlinear_kernel<<<grid, block, 0, stream>>>(x, wq, scale, out);
}